// Round 10
// baseline (416.565 us; speedup 1.0000x reference)
//
#include <hip/hip_runtime.h>

typedef unsigned int u32;
typedef unsigned short u16;
typedef short bf16x8 __attribute__((ext_vector_type(8)));
typedef float f32x4 __attribute__((ext_vector_type(4)));
typedef unsigned short u16x4 __attribute__((ext_vector_type(4)));

#define KOFF 27

__device__ __forceinline__ float bf2f(u16 u) {
    u32 x = ((u32)u) << 16;
    return __builtin_bit_cast(float, x);
}
__device__ __forceinline__ u16 f2bf(float f) {
    u32 u = __builtin_bit_cast(u32, f);
    u32 r = (u + 0x7FFFu + ((u >> 16) & 1u)) >> 16;  // RNE
    return (u16)r;
}
__device__ __forceinline__ void async16(void* lds, const void* g) {
    __builtin_amdgcn_global_load_lds(
        (const __attribute__((address_space(1))) u32*)g,
        (__attribute__((address_space(3))) u32*)lds, 16, 0, 0);
}

// ---------------------------------------------------------------------------
// Mega prep (unchanged — proven).  W2 byte layout:
//   byte = (kslc*2+cg)*8192 + n*2048 + kk2*1024 + lane*16  holding bf16
//   W[k][c][d]: d = cg*64+n*16+(lane&15), c = kslc*64+kk2*32+(lane>>4)*8+j
//  blocks 540..543: h0W1/h1W1 -> Wt2[256][128] bf16 swizzled (head L1 concat)
//  blocks 544..545: h0W2/h1W2 -> wt2h [2][16][128] bf16 swizzled
//  blocks 546..553: E1[16][128] = s1emb @ h1W1 (fp32, exact)
// ---------------------------------------------------------------------------
struct PrepArgs {
    const float* ws[12];  // 10 conv W + h0W1 + h1W1
    u16* wd[12];          // 10 conv W2 + Wt2 halves
    const float* h0W2;
    const float* h1W2;
    u16* wt2h;
    const float* s1emb;
    const float* h1W1f;
    float* E1;
};
__global__ __launch_bounds__(256) void prep_mega(PrepArgs a) {
    __shared__ float t[128][65];  // [c][d_local]
    const int bid = blockIdx.x;
    if (bid < 540) {
        const int w = bid / 54, r = bid % 54;
        const int k = r >> 1, cg = r & 1;
        const float* s = a.ws[w] + k * 16384 + cg * 64;
        for (int i = threadIdx.x; i < 8192; i += 256) {
            int c = i >> 6, dl = i & 63;
            t[c][dl] = s[c * 128 + dl];
        }
        __syncthreads();
        u16* ob = a.wd[w] + k * 16384;
        for (int sl = threadIdx.x; sl < 1024; sl += 256) {
            int lane = sl & 63, kk2 = (sl >> 6) & 1, n = (sl >> 7) & 3,
                kslc = (sl >> 9) & 1;
            int S = (((kslc * 2 + cg) * 4 + n) * 2 + kk2) * 64 + lane;
            int dl = n * 16 + (lane & 15);
            int c0 = kslc * 64 + kk2 * 32 + (lane >> 4) * 8;
            u16x4 v0, v1;
#pragma unroll
            for (int j = 0; j < 4; ++j) v0[j] = f2bf(t[c0 + j][dl]);
#pragma unroll
            for (int j = 0; j < 4; ++j) v1[j] = f2bf(t[c0 + 4 + j][dl]);
            *(u16x4*)(ob + S * 8) = v0;
            *(u16x4*)(ob + S * 8 + 4) = v1;
        }
    } else if (bid < 544) {
        int r = bid - 540;
        int w = 10 + (r >> 1), half = r & 1;
        const float* s = a.ws[w] + half * 64;
        for (int i = threadIdx.x; i < 8192; i += 256) {
            int c = i >> 6, dl = i & 63;
            t[c][dl] = s[c * 128 + dl];
        }
        __syncthreads();
        u16* db = a.wd[w];
        for (int i = threadIdx.x; i < 8192; i += 256) {
            int dl = i >> 7, c = i & 127;
            int d = half * 64 + dl;
            db[d * 128 + (c ^ ((d & 7) << 3))] = f2bf(t[c][dl]);
        }
    } else if (bid < 546) {
        int h = bid - 544;
        const float* src = h ? a.h1W2 : a.h0W2;
        u16* dst = a.wt2h + h * 2048;
        for (int i = threadIdx.x; i < 2048; i += 256) {
            int j = i >> 7, d = i & 127;
            dst[j * 128 + (d ^ ((j & 7) << 3))] = f2bf(src[d * 16 + j]);
        }
    } else {
        int b = bid - 546;  // 0..7
        int r = b * 2 + (threadIdx.x >> 7);
        int c = threadIdx.x & 127;
        float acc = 0.f;
        for (int kx = 0; kx < 128; ++kx)
            acc = fmaf(a.s1emb[r * 128 + kx], a.h1W1f[kx * 128 + c], acc);
        a.E1[r * 128 + c] = acc;
    }
}

// f0[n][c] = prior_emb[x_O[n]][c]  (fp32 -> bf16)
__global__ __launch_bounds__(256) void embed_k(const int* __restrict__ xO,
                                               const float* __restrict__ emb,
                                               u16* __restrict__ out) {
    int idx = blockIdx.x * 256 + threadIdx.x;
    int c = idx & 127, n = idx >> 7;
    out[idx] = f2bf(emb[xO[n] * 128 + c]);
}

// g[m][c] = f[m>>3][c] + oct_emb[child_oct[m]][c]
__global__ __launch_bounds__(256) void expand_k(const u16* __restrict__ f,
                                                const int* __restrict__ oct,
                                                const float* __restrict__ oemb,
                                                u16* __restrict__ g) {
    int idx = blockIdx.x * 256 + threadIdx.x;
    int c = idx & 127, m = idx >> 7;
    g[idx] = f2bf(bf2f(f[(m >> 3) * 128 + c]) + oemb[oct[m] * 128 + c]);
}

#define LOADB(dst, vb, imm)                                      \
    asm volatile("global_load_dwordx4 %0, %1, %2 offset:" #imm   \
                 : "=&v"(dst)                                    \
                 : "v"(vb), "s"(wk)                              \
                 : "memory")

// ---------------------------------------------------------------------------
// conv7 (wave-independent pipelines): BM=64 pts/block, 256 thr (4 waves).
// Wave (rg=wid>>1, cg=wid&1) owns output rows rg*32..+32, cols cg*64..+64
// over FULL K=128.  NO barriers in the K-loop:
//  - A: per-wave PRIVATE 8KB LDS region, double-buffered, gathered via
//    per-lane-source global_load_lds (pre-swizzled source, linear dest).
//  - B: 16 frags (64 cols x K=128) in registers, DOUBLE-buffered, coalesced
//    1KB global_load_dwordx4 from W2 via 4 VGPR bases + imm<=3072 (13-bit).
// Per-wave per-iter VMEM = 8 (A) + 16 (B) = 24 issues -> s_waitcnt vmcnt(24)
// waits only for data issued ONE FULL ITERATION earlier (latency hidden;
// 8 independent wave-pipelines per CU at 2 blocks/CU).
// LDS = 64KB (A) + 6.9KB (nbr) -> 2 blocks/CU.  VGPR ~200 < 256 @ (256,2).
// PARTIAL: split-K over 8 offset groups (blockIdx.y), fp32 partials.
// ---------------------------------------------------------------------------
template <bool PARTIAL>
__global__ __launch_bounds__(256, 2) void conv7(
    const u16* __restrict__ fin, const int* __restrict__ nbr,
    const u16* __restrict__ wt, const u16* __restrict__ res,
    u16* __restrict__ fout, float* __restrict__ pout, int npts) {
    constexpr int BM = 64;
    __shared__ __align__(16) u16 Asb[2][4][4096];  // [buf][wave][32*128]
    __shared__ int nbrS[BM * KOFF];                // 6912 B
    const int tid = threadIdx.x;
    const int wid = tid >> 6;
    const int lane = tid & 63;
    const int p0 = blockIdx.x * BM;
    const int g = PARTIAL ? blockIdx.y : 0;
    const int k0 = PARTIAL ? (g * KOFF) >> 3 : 0;
    const int k1 = PARTIAL ? ((g + 1) * KOFF) >> 3 : KOFF;

    for (int i = tid; i < BM * KOFF; i += 256)
        nbrS[i] = nbr[(p0 + i / KOFF) * KOFF + (i % KOFF)];
    __syncthreads();  // the ONLY block barrier; vmcnt==0 past this point

    f32x4 acc[2][4];
#pragma unroll
    for (int m = 0; m < 2; ++m)
#pragma unroll
        for (int n = 0; n < 4; ++n) acc[m][n] = f32x4{0.f, 0.f, 0.f, 0.f};

    const int rg0 = (wid >> 1) * 32;  // wave row base within block
    const int cg = wid & 1;           // wave col group (64 cols)
    const int lrow = lane & 15;
    const int lkb = (lane >> 4) * 16;
    // W2 bases: byte = (kslc*2+cg)*8192 + n*2048 + kk2*1024 + lane*16
    const int b0a = cg * 8192 + lane * 16;  // kslc=0, n=0..1
    const int b0b = b0a + 4096;             // kslc=0, n=2..3
    const int b1a = b0a + 16384;            // kslc=1, n=0..1
    const int b1b = b1a + 4096;             // kslc=1, n=2..3

    auto stageA = [&](int k, int buf) {
        char* db = (char*)&Asb[buf][wid][0];
#pragma unroll
        for (int i = 0; i < 8; ++i) {
            int rl = i * 4 + (lane >> 4);  // local row 0..31
            int cbs = ((lane & 15) * 16) ^ ((rl & 7) << 4);
            int rgl = nbrS[(rg0 + rl) * KOFF + k];
            async16(db + i * 1024, (const char*)fin + (size_t)rgl * 256 + cbs);
        }
    };
    // 16 coalesced 1KB loads; frag B[n*4+kk] = channels kk*32..+32, cols
    // cg*64+n*16..+16 (kslc=kk>>1 -> +16384, kk2=kk&1 -> +1024, n -> +2048)
    auto loadB = [&](int k, bf16x8 (&B)[16]) {
        const u16* wk = wt + k * 16384;
        LOADB(B[0], b0a, 0);
        LOADB(B[1], b0a, 1024);
        LOADB(B[2], b1a, 0);
        LOADB(B[3], b1a, 1024);
        LOADB(B[4], b0a, 2048);
        LOADB(B[5], b0a, 3072);
        LOADB(B[6], b1a, 2048);
        LOADB(B[7], b1a, 3072);
        LOADB(B[8], b0b, 0);
        LOADB(B[9], b0b, 1024);
        LOADB(B[10], b1b, 0);
        LOADB(B[11], b1b, 1024);
        LOADB(B[12], b0b, 2048);
        LOADB(B[13], b0b, 3072);
        LOADB(B[14], b1b, 2048);
        LOADB(B[15], b1b, 3072);
    };

    bf16x8 Ba[16], Bb[16];
    stageA(k0, 0);
    loadB(k0, Ba);

    auto body = [&](bf16x8 (&Bc)[16], bf16x8 (&Bn)[16], int k) {
        const int ab = (k - k0) & 1;
        if (k + 1 < k1) {
            stageA(k + 1, ab ^ 1);
            loadB(k + 1, Bn);
            // 24 just issued stay in flight; waits for iter k's A+B only
            asm volatile("s_waitcnt vmcnt(24)" ::: "memory");
        } else {
            asm volatile("s_waitcnt vmcnt(0)" ::: "memory");
        }
        __builtin_amdgcn_sched_barrier(0);  // no ds_read hoisting above wait
        const char* AsW = (const char*)&Asb[ab][wid][0];
        __builtin_amdgcn_s_setprio(1);
#pragma unroll
        for (int kk = 0; kk < 4; ++kk) {
            bf16x8 av[2];
#pragma unroll
            for (int m = 0; m < 2; ++m) {
                int row = m * 16 + lrow;
                int cb = (kk * 64 + lkb) ^ ((row & 7) << 4);
                av[m] = *(const bf16x8*)(AsW + row * 256 + cb);
            }
#pragma unroll
            for (int m = 0; m < 2; ++m)
#pragma unroll
                for (int n = 0; n < 4; ++n)
                    acc[m][n] = __builtin_amdgcn_mfma_f32_16x16x32_bf16(
                        av[m], Bc[n * 4 + kk], acc[m][n], 0, 0, 0);
        }
        __builtin_amdgcn_s_setprio(0);
    };

    int k = k0;
    while (true) {
        body(Ba, Bb, k);
        if (++k >= k1) break;
        body(Bb, Ba, k);
        if (++k >= k1) break;
    }

    // epilogue (wave-local, no reduce).  D: col=lane&15, row=(lane>>4)*4+q
    if constexpr (PARTIAL) {
        float* pg = pout + (size_t)g * npts * 128;
#pragma unroll
        for (int m = 0; m < 2; ++m) {
            int prow = p0 + rg0 + m * 16 + (lane >> 4) * 4;
#pragma unroll
            for (int n = 0; n < 4; ++n) {
                int dcol = cg * 64 + n * 16 + lrow;
#pragma unroll
                for (int q = 0; q < 4; ++q)
                    pg[(prow + q) * 128 + dcol] = acc[m][n][q];
            }
        }
    } else {
#pragma unroll
        for (int m = 0; m < 2; ++m) {
            int prow = p0 + rg0 + m * 16 + (lane >> 4) * 4;
#pragma unroll
            for (int n = 0; n < 4; ++n) {
                int dcol = cg * 64 + n * 16 + lrow;
#pragma unroll
                for (int q = 0; q < 4; ++q) {
                    float v = acc[m][n][q];
                    int p = prow + q;
                    if (res) v += bf2f(res[p * 128 + dcol]);
                    v = v > 0.f ? v : 0.f;
                    fout[p * 128 + dcol] = f2bf(v);
                }
            }
        }
    }
}

// combine split-K partials: out = relu(sum_g P[g] (+ res)) -> bf16
__global__ __launch_bounds__(256) void combine_k(const float* __restrict__ P,
                                                 const u16* __restrict__ res,
                                                 u16* __restrict__ fout,
                                                 int nelem) {
    int base = (blockIdx.x * 256 + threadIdx.x) * 4;
    f32x4 s = *(const f32x4*)(P + base);
#pragma unroll
    for (int gg = 1; gg < 8; ++gg)
        s += *(const f32x4*)(P + (size_t)gg * nelem + base);
    u16x4 o;
    if (res) {
        u16x4 rv = *(const u16x4*)(res + base);
#pragma unroll
        for (int j = 0; j < 4; ++j) s[j] += bf2f(rv[j]);
    }
#pragma unroll
    for (int j = 0; j < 4; ++j) {
        float v = s[j] > 0.f ? s[j] : 0.f;
        o[j] = f2bf(v);
    }
    *(u16x4*)(fout + base) = o;
}

// ---------------------------------------------------------------------------
// Fused heads: one block = 128 points (unchanged, proven).
// ---------------------------------------------------------------------------
__global__ __launch_bounds__(512, 1) void fused_heads(
    const u16* __restrict__ G, const int* __restrict__ gtO,
    const u16* __restrict__ wt2, const u16* __restrict__ wt2h,
    const float* __restrict__ b1a, const float* __restrict__ b1b,
    const float* __restrict__ E1, const float* __restrict__ b2a,
    const float* __restrict__ b2b, float* __restrict__ partial) {
    __shared__ __align__(16) u16 AB[49152];   // 96KB: A 32K | B 64K
    __shared__ __align__(16) u16 W2ts[4096];  // 8KB: [2][16][128] swizzled
    __shared__ float E1s[2048];
    __shared__ float b2s[32];
    __shared__ int gts[256];
    __shared__ float bitsS[256];
    u16* Asb = AB;
    u16* Bsb = AB + 16384;
    char* Hb = (char*)AB;  // 128 rows x 512B, aliases A+B (dead after MFMA1)
    const int tid = threadIdx.x, wid = tid >> 6, lane = tid & 63;
    const int lrow = lane & 15, lkb = (lane >> 4) * 16;
    const int p0 = blockIdx.x * 128;

#pragma unroll
    for (int i = 0; i < 4; ++i) {
        int o = i * 8192 + tid * 16;
        int r = o >> 8;
        int cbs = (o & 255) ^ ((r & 7) << 4);
        async16((char*)Asb + i * 8192 + wid * 1024,
                (const char*)G + (size_t)(p0 + r) * 256 + cbs);
    }
#pragma unroll
    for (int i = 0; i < 8; ++i)
        async16((char*)Bsb + i * 8192 + wid * 1024,
                (const char*)wt2 + i * 8192 + tid * 16);
    async16((char*)W2ts + wid * 1024, (const char*)wt2h + tid * 16);
    for (int i = tid; i < 2048; i += 512) E1s[i] = E1[i];
    if (tid < 16) b2s[tid] = b2a[tid];
    else if (tid < 32) b2s[tid] = b2b[tid - 16];
    if (tid < 128) {
        int g = gtO[p0 + tid];
        gts[tid] = g & 15;
        gts[128 + tid] = g >> 4;
    }
    __syncthreads();

    const int RB = (wid >> 1) * 32, CB = (wid & 1) * 128;
    f32x4 acc[2][8];
#pragma unroll
    for (int m = 0; m < 2; ++m)
#pragma unroll
        for (int n = 0; n < 8; ++n) acc[m][n] = f32x4{0.f, 0.f, 0.f, 0.f};
    __builtin_amdgcn_s_setprio(1);
#pragma unroll
    for (int kk = 0; kk < 4; ++kk) {
        bf16x8 av[2], bv[8];
#pragma unroll
        for (int m = 0; m < 2; ++m) {
            int row = RB + m * 16 + lrow;
            int cb = (kk * 64 + lkb) ^ ((row & 7) << 4);
            av[m] = *(const bf16x8*)((const char*)Asb + row * 256 + cb);
        }
#pragma unroll
        for (int n = 0; n < 8; ++n) {
            int drow = CB + n * 16 + lrow;
            int cb = (kk * 64 + lkb) ^ ((drow & 7) << 4);
            bv[n] = *(const bf16x8*)((const char*)Bsb + drow * 256 + cb);
        }
#pragma unroll
        for (int m = 0; m < 2; ++m)
#pragma unroll
            for (int n = 0; n < 8; ++n)
                acc[m][n] = __builtin_amdgcn_mfma_f32_16x16x32_bf16(
                    av[m], bv[n], acc[m][n], 0, 0, 0);
    }
    __builtin_amdgcn_s_setprio(0);
    __syncthreads();  // everyone done reading A/B -> H may overwrite

    const float* b1p = CB ? b1b : b1a;
    float b1v[8];
#pragma unroll
    for (int n = 0; n < 8; ++n) b1v[n] = b1p[n * 16 + lrow];
#pragma unroll
    for (int m = 0; m < 2; ++m) {
#pragma unroll
        for (int q = 0; q < 4; ++q) {
            int p = RB + m * 16 + (lane >> 4) * 4 + q;
#pragma unroll
            for (int n = 0; n < 8; ++n) {
                float v = acc[m][n][q] + b1v[n];
                if (CB) v += E1s[gts[p] * 128 + n * 16 + lrow];
                v = v > 0.f ? v : 0.f;
                int colb = (CB + n * 16 + lrow) * 2;
                *(u16*)(Hb + p * 512 + (colb ^ ((p & 7) << 4))) = f2bf(v);
            }
        }
    }
    __syncthreads();

    const int RB2 = wid * 16;
    f32x4 acc2[2];
    acc2[0] = f32x4{0.f, 0.f, 0.f, 0.f};
    acc2[1] = f32x4{0.f, 0.f, 0.f, 0.f};
#pragma unroll
    for (int kk = 0; kk < 4; ++kk) {
        int row = RB2 + lrow;
        int cb = (kk * 64 + lkb) ^ ((row & 7) << 4);
        int cbw = (kk * 64 + lkb) ^ ((lrow & 7) << 4);
#pragma unroll
        for (int h = 0; h < 2; ++h) {
            bf16x8 a2 = *(const bf16x8*)(Hb + row * 512 + h * 256 + cb);
            bf16x8 b2v = *(const bf16x8*)((const char*)W2ts + h * 4096 +
                                          lrow * 256 + cbw);
            acc2[h] = __builtin_amdgcn_mfma_f32_16x16x32_bf16(a2, b2v, acc2[h],
                                                              0, 0, 0);
        }
    }
    const int jj = lrow;
#pragma unroll
    for (int h = 0; h < 2; ++h) {
#pragma unroll
        for (int q = 0; q < 4; ++q) {
            int pt = RB2 + (lane >> 4) * 4 + q;
            float v = acc2[h][q] + b2s[h * 16 + jj];
            float mx = v;
#pragma unroll
            for (int o = 1; o < 16; o <<= 1) mx = fmaxf(mx, __shfl_xor(mx, o, 16));
            float e = expf(v - mx);
            float s = e;
#pragma unroll
            for (int o = 1; o < 16; o <<= 1) s += __shfl_xor(s, o, 16);
            float bits = -log2f(e / s + 1e-10f);
            bits = fminf(fmaxf(bits, 0.f), 50.f);
            if (jj == gts[h * 128 + pt]) bitsS[h * 128 + pt] = bits;
        }
    }
    __syncthreads();
    if (tid < 64) {
        float s = bitsS[tid] + bitsS[tid + 64] + bitsS[tid + 128] + bitsS[tid + 192];
#pragma unroll
        for (int o = 32; o > 0; o >>= 1) s += __shfl_down(s, o, 64);
        if (tid == 0) partial[blockIdx.x] = s;
    }
}

__global__ __launch_bounds__(256) void finalize_k(const float* __restrict__ partial,
                                                  float* __restrict__ out, int n) {
    float s = 0.f;
    for (int i = threadIdx.x; i < n; i += 256) s += partial[i];
#pragma unroll
    for (int o = 32; o > 0; o >>= 1) s += __shfl_down(s, o, 64);
    __shared__ float wsum[4];
    if ((threadIdx.x & 63) == 0) wsum[threadIdx.x >> 6] = s;
    __syncthreads();
    if (threadIdx.x == 0)
        out[0] = (wsum[0] + wsum[1] + wsum[2] + wsum[3]) * (1.0f / 4096.0f);
}

// ---------------------------------------------------------------------------
extern "C" void kernel_launch(void* const* d_in, const int* in_sizes, int n_in,
                              void* d_out, int out_size, void* d_ws,
                              size_t ws_size, hipStream_t stream) {
    const int N = 4096, M = 32768;
    const int* x_O = (const int*)d_in[0];
    const int* gt_O = (const int*)d_in[1];
    const int* nbr_par = (const int*)d_in[2];
    const int* nbr_ch = (const int*)d_in[3];
    const int* child_oct = (const int*)d_in[4];
    const float* prior_emb = (const float*)d_in[5];
    const float* convW[10] = {
        (const float*)d_in[6],  (const float*)d_in[7],  (const float*)d_in[8],
        (const float*)d_in[9],  (const float*)d_in[10], (const float*)d_in[12],
        (const float*)d_in[13], (const float*)d_in[14], (const float*)d_in[15],
        (const float*)d_in[16]};
    const float* oct_emb = (const float*)d_in[11];
    const float* s1_emb = (const float*)d_in[17];
    const float* h0W1 = (const float*)d_in[18];
    const float* h0b1 = (const float*)d_in[19];
    const float* h0W2 = (const float*)d_in[20];
    const float* h0b2 = (const float*)d_in[21];
    const float* h1W1 = (const float*)d_in[22];
    const float* h1b1 = (const float*)d_in[23];
    const float* h1W2 = (const float*)d_in[24];
    const float* h1b2 = (const float*)d_in[25];

    char* ws = (char*)d_ws;
    size_t off = 0;
    auto alloc = [&](size_t b) {
        void* p = ws + off;
        off += (b + 255) & ~(size_t)255;
        return p;
    };
    PrepArgs pa;
    for (int i = 0; i < 10; ++i) {
        pa.ws[i] = convW[i];
        pa.wd[i] = (u16*)alloc(27 * 128 * 128 * 2);
    }
    u16* Wt2 = (u16*)alloc(256 * 128 * 2);
    pa.ws[10] = h0W1;
    pa.ws[11] = h1W1;
    pa.wd[10] = Wt2;
    pa.wd[11] = Wt2 + 128 * 128;
    u16* wt2h = (u16*)alloc(2 * 16 * 128 * 2);
    float* E1 = (float*)alloc(16 * 128 * 4);
    pa.h0W2 = h0W2;
    pa.h1W2 = h1W2;
    pa.wt2h = wt2h;
    pa.s1emb = s1_emb;
    pa.h1W1f = h1W1;
    pa.E1 = E1;

    u16* fA = (u16*)alloc((size_t)N * 256);
    u16* fB = (u16*)alloc((size_t)N * 256);
    u16* fC = (u16*)alloc((size_t)N * 256);
    u16* gA = (u16*)alloc((size_t)M * 256);
    u16* gB = (u16*)alloc((size_t)M * 256);
    u16* gC = (u16*)alloc((size_t)M * 256);
    float* partial = (float*)alloc(256 * 4);
    // split-K parent partials (8 * N * 128 fp32 = 16MB) alias gA+gB (dead
    // until expand_k / child conv #1 write them after the parent stack).
    float* pconv = (float*)gA;

    prep_mega<<<554, 256, 0, stream>>>(pa);
    embed_k<<<N * 128 / 256, 256, 0, stream>>>(x_O, prior_emb, fA);

    const int PE = N * 128;
    // parent stack: conv7 split-K over 8 offset groups, grid (64,8)=512
    conv7<true><<<dim3(64, 8), 256, 0, stream>>>(fA, nbr_par, pa.wd[0], nullptr, nullptr, pconv, N);
    combine_k<<<PE / 1024, 256, 0, stream>>>(pconv, nullptr, fB, PE);
    conv7<true><<<dim3(64, 8), 256, 0, stream>>>(fB, nbr_par, pa.wd[1], nullptr, nullptr, pconv, N);
    combine_k<<<PE / 1024, 256, 0, stream>>>(pconv, nullptr, fC, PE);
    conv7<true><<<dim3(64, 8), 256, 0, stream>>>(fC, nbr_par, pa.wd[2], nullptr, nullptr, pconv, N);
    combine_k<<<PE / 1024, 256, 0, stream>>>(pconv, fB, fA, PE);
    conv7<true><<<dim3(64, 8), 256, 0, stream>>>(fA, nbr_par, pa.wd[3], nullptr, nullptr, pconv, N);
    combine_k<<<PE / 1024, 256, 0, stream>>>(pconv, nullptr, fC, PE);
    conv7<true><<<dim3(64, 8), 256, 0, stream>>>(fC, nbr_par, pa.wd[4], nullptr, nullptr, pconv, N);
    combine_k<<<PE / 1024, 256, 0, stream>>>(pconv, fA, fB, PE);

    // expand to children
    expand_k<<<M * 128 / 256, 256, 0, stream>>>(fB, child_oct, oct_emb, gA);

    // child stack: conv7 full-K, 512 blocks (2 per CU, 8 wave-pipelines/CU)
    conv7<false><<<dim3(512, 1), 256, 0, stream>>>(gA, nbr_ch, pa.wd[5], nullptr, gB, nullptr, M);
    conv7<false><<<dim3(512, 1), 256, 0, stream>>>(gB, nbr_ch, pa.wd[6], nullptr, gC, nullptr, M);
    conv7<false><<<dim3(512, 1), 256, 0, stream>>>(gC, nbr_ch, pa.wd[7], gB, gA, nullptr, M);
    conv7<false><<<dim3(512, 1), 256, 0, stream>>>(gA, nbr_ch, pa.wd[8], nullptr, gC, nullptr, M);
    conv7<false><<<dim3(512, 1), 256, 0, stream>>>(gC, nbr_ch, pa.wd[9], gA, gB, nullptr, M);

    fused_heads<<<M / 128, 512, 0, stream>>>(gB, gt_O, Wt2, wt2h, h0b1, h1b1,
                                             E1, h0b2, h1b2, partial);
    finalize_k<<<1, 256, 0, stream>>>(partial, (float*)d_out, 256);

    (void)in_sizes; (void)n_in; (void)out_size; (void)ws_size;
}

// Round 11
// 301.228 us; speedup vs baseline: 1.3829x; 1.3829x over previous
//
#include <hip/hip_runtime.h>

typedef unsigned int u32;
typedef unsigned short u16;
typedef unsigned char u8;
typedef short bf16x8 __attribute__((ext_vector_type(8)));
typedef float f32x4 __attribute__((ext_vector_type(4)));
typedef unsigned short u16x4 __attribute__((ext_vector_type(4)));
typedef long lx2 __attribute__((ext_vector_type(2)));

#define KOFF 27

__device__ __forceinline__ float bf2f(u16 u) {
    u32 x = ((u32)u) << 16;
    return __builtin_bit_cast(float, x);
}
__device__ __forceinline__ u16 f2bf(float f) {
    u32 u = __builtin_bit_cast(u32, f);
    u32 r = (u + 0x7FFFu + ((u >> 16) & 1u)) >> 16;  // RNE
    return (u16)r;
}
// f32 -> OCP e4m3fn, RNE, saturate to 448
__device__ __forceinline__ u8 f2fp8(float f) {
    u32 u = __builtin_bit_cast(u32, f);
    u32 sign = (u >> 24) & 0x80u;
    float a = fabsf(f);
    if (a >= 448.f) return (u8)(sign | 0x7Eu);
    if (a < 0.015625f) {  // subnormal: round(a*2^9), 0..8 (8 -> min normal)
        int q = (int)rintf(a * 512.f);
        return (u8)(sign | (u32)q);
    }
    u32 m = u & 0x7FFFFFFFu;
    m += 0x7FFFFu + ((m >> 20) & 1u);  // RNE at bit 20
    u32 e8 = (m >> 23) - 120u;
    if (e8 >= 16u) return (u8)(sign | 0x7Eu);
    return (u8)(sign | (e8 << 3) | ((m >> 20) & 7u));
}
__device__ __forceinline__ float fp82f(u8 v) {
    u32 s = ((u32)(v & 0x80)) << 24;
    u32 em = v & 0x7Fu;
    float mag;
    if (em < 8)
        mag = (float)em * 0.001953125f;  // k * 2^-9
    else
        mag = __builtin_bit_cast(float,
                                 (((em >> 3) + 120u) << 23) | ((em & 7u) << 20));
    return __builtin_bit_cast(float, __builtin_bit_cast(u32, mag) | s);
}
__device__ __forceinline__ void async16(void* lds, const void* g) {
    __builtin_amdgcn_global_load_lds(
        (const __attribute__((address_space(1))) u32*)g,
        (__attribute__((address_space(3))) u32*)lds, 16, 0, 0);
}

// ---------------------------------------------------------------------------
// Mega prep.
//  bid 0..269   : parent conv W (w=bid/54) -> bf16 W2 layout (proven):
//     byte=(kslc*2+cg)*8192+n*2048+kk2*1024+lane*16, bf16 W[k][c][d],
//     d=cg*64+n*16+(lane&15), c=kslc*64+kk2*32+(lane>>4)*8+j
//  bid 270..539 : child conv W (w=5+(bid-270)/54) -> fp8 W3 layout:
//     byte=(kslc*2+cg)*4096+n*1024+lane*16+kk2*8+j, e4m3 W[k][c][d],
//     d=cg*64+n*16+(lane&15), c=kslc*64+kk2*32+(lane>>4)*8+j
//  bid 540..543 : h0W1/h1W1 -> Wt2[256][128] bf16 swizzled
//  bid 544..545 : h0W2/h1W2 -> wt2h [2][16][128] bf16 swizzled
//  bid 546..553 : E1[16][128] = s1emb @ h1W1 (fp32)
// ---------------------------------------------------------------------------
struct PrepArgs {
    const float* ws[12];  // 10 conv W + h0W1 + h1W1
    u16* wd[12];          // parent W2 (0..4) + Wt2 halves (10,11)
    u8* wd3[5];           // child W3
    const float* h0W2;
    const float* h1W2;
    u16* wt2h;
    const float* s1emb;
    const float* h1W1f;
    float* E1;
};
__global__ __launch_bounds__(256) void prep_mega(PrepArgs a) {
    __shared__ float t[128][65];  // [c][d_local]
    const int bid = blockIdx.x;
    if (bid < 270) {  // parent W2 (bf16)
        const int w = bid / 54, r = bid % 54;
        const int k = r >> 1, cg = r & 1;
        const float* s = a.ws[w] + k * 16384 + cg * 64;
        for (int i = threadIdx.x; i < 8192; i += 256) {
            int c = i >> 6, dl = i & 63;
            t[c][dl] = s[c * 128 + dl];
        }
        __syncthreads();
        u16* ob = a.wd[w] + k * 16384;
        for (int sl = threadIdx.x; sl < 1024; sl += 256) {
            int lane = sl & 63, kk2 = (sl >> 6) & 1, n = (sl >> 7) & 3,
                kslc = (sl >> 9) & 1;
            int S = (((kslc * 2 + cg) * 4 + n) * 2 + kk2) * 64 + lane;
            int dl = n * 16 + (lane & 15);
            int c0 = kslc * 64 + kk2 * 32 + (lane >> 4) * 8;
            u16x4 v0, v1;
#pragma unroll
            for (int j = 0; j < 4; ++j) v0[j] = f2bf(t[c0 + j][dl]);
#pragma unroll
            for (int j = 0; j < 4; ++j) v1[j] = f2bf(t[c0 + 4 + j][dl]);
            *(u16x4*)(ob + S * 8) = v0;
            *(u16x4*)(ob + S * 8 + 4) = v1;
        }
    } else if (bid < 540) {  // child W3 (fp8)
        const int idx = bid - 270;
        const int w5 = idx / 54, r = idx % 54;
        const int k = r >> 1, cg = r & 1;
        const float* s = a.ws[5 + w5] + k * 16384 + cg * 64;
        for (int i = threadIdx.x; i < 8192; i += 256) {
            int c = i >> 6, dl = i & 63;
            t[c][dl] = s[c * 128 + dl];
        }
        __syncthreads();
        u8* ob = a.wd3[w5] + k * 16384;
        for (int sl = threadIdx.x; sl < 8192; sl += 256) {
            int j = sl & 7, lane = (sl >> 3) & 63, kk2 = (sl >> 9) & 1,
                n = (sl >> 10) & 3, kslc = (sl >> 12) & 1;
            int c = kslc * 64 + kk2 * 32 + (lane >> 4) * 8 + j;
            int dl = n * 16 + (lane & 15);
            int byte = (kslc * 2 + cg) * 4096 + n * 1024 + lane * 16 + kk2 * 8 + j;
            ob[byte] = f2fp8(t[c][dl]);
        }
    } else if (bid < 544) {
        int r = bid - 540;
        int w = 10 + (r >> 1), half = r & 1;
        const float* s = a.ws[w] + half * 64;
        for (int i = threadIdx.x; i < 8192; i += 256) {
            int c = i >> 6, dl = i & 63;
            t[c][dl] = s[c * 128 + dl];
        }
        __syncthreads();
        u16* db = a.wd[w];
        for (int i = threadIdx.x; i < 8192; i += 256) {
            int dl = i >> 7, c = i & 127;
            int d = half * 64 + dl;
            db[d * 128 + (c ^ ((d & 7) << 3))] = f2bf(t[c][dl]);
        }
    } else if (bid < 546) {
        int h = bid - 544;
        const float* src = h ? a.h1W2 : a.h0W2;
        u16* dst = a.wt2h + h * 2048;
        for (int i = threadIdx.x; i < 2048; i += 256) {
            int j = i >> 7, d = i & 127;
            dst[j * 128 + (d ^ ((j & 7) << 3))] = f2bf(src[d * 16 + j]);
        }
    } else {
        int b = bid - 546;  // 0..7
        int r = b * 2 + (threadIdx.x >> 7);
        int c = threadIdx.x & 127;
        float acc = 0.f;
        for (int kx = 0; kx < 128; ++kx)
            acc = fmaf(a.s1emb[r * 128 + kx], a.h1W1f[kx * 128 + c], acc);
        a.E1[r * 128 + c] = acc;
    }
}

// f0[n][c] = prior_emb[x_O[n]][c]  (fp32 -> bf16)
__global__ __launch_bounds__(256) void embed_k(const int* __restrict__ xO,
                                               const float* __restrict__ emb,
                                               u16* __restrict__ out) {
    int idx = blockIdx.x * 256 + threadIdx.x;
    int c = idx & 127, n = idx >> 7;
    out[idx] = f2bf(emb[xO[n] * 128 + c]);
}

// g8[m][c] = fp8( f[m>>3][c] + oct_emb[child_oct[m]][c] )
__global__ __launch_bounds__(256) void expand8(const u16* __restrict__ f,
                                               const int* __restrict__ oct,
                                               const float* __restrict__ oemb,
                                               u8* __restrict__ g) {
    int idx = blockIdx.x * 256 + threadIdx.x;
    int c = idx & 127, m = idx >> 7;
    g[idx] = f2fp8(bf2f(f[(m >> 3) * 128 + c]) + oemb[oct[m] * 128 + c]);
}

#define LOADB(dst, vb, imm)                                      \
    asm volatile("global_load_dwordx4 %0, %1, %2 offset:" #imm   \
                 : "=&v"(dst)                                    \
                 : "v"(vb), "s"(wk)                              \
                 : "memory")

// ---------------------------------------------------------------------------
// conv7 (bf16, PROVEN R10): parents only.  Split-K over 8 offset groups.
// ---------------------------------------------------------------------------
template <bool PARTIAL>
__global__ __launch_bounds__(256, 2) void conv7(
    const u16* __restrict__ fin, const int* __restrict__ nbr,
    const u16* __restrict__ wt, const u16* __restrict__ res,
    u16* __restrict__ fout, float* __restrict__ pout, int npts) {
    constexpr int BM = 64;
    __shared__ __align__(16) u16 Asb[2][4][4096];
    __shared__ int nbrS[BM * KOFF];
    const int tid = threadIdx.x;
    const int wid = tid >> 6;
    const int lane = tid & 63;
    const int p0 = blockIdx.x * BM;
    const int g = PARTIAL ? blockIdx.y : 0;
    const int k0 = PARTIAL ? (g * KOFF) >> 3 : 0;
    const int k1 = PARTIAL ? ((g + 1) * KOFF) >> 3 : KOFF;

    for (int i = tid; i < BM * KOFF; i += 256)
        nbrS[i] = nbr[(p0 + i / KOFF) * KOFF + (i % KOFF)];
    __syncthreads();

    f32x4 acc[2][4];
#pragma unroll
    for (int m = 0; m < 2; ++m)
#pragma unroll
        for (int n = 0; n < 4; ++n) acc[m][n] = f32x4{0.f, 0.f, 0.f, 0.f};

    const int rg0 = (wid >> 1) * 32;
    const int cg = wid & 1;
    const int lrow = lane & 15;
    const int lkb = (lane >> 4) * 16;
    const int b0a = cg * 8192 + lane * 16;
    const int b0b = b0a + 4096;
    const int b1a = b0a + 16384;
    const int b1b = b1a + 4096;

    auto stageA = [&](int k, int buf) {
        char* db = (char*)&Asb[buf][wid][0];
#pragma unroll
        for (int i = 0; i < 8; ++i) {
            int rl = i * 4 + (lane >> 4);
            int cbs = ((lane & 15) * 16) ^ ((rl & 7) << 4);
            int rgl = nbrS[(rg0 + rl) * KOFF + k];
            async16(db + i * 1024, (const char*)fin + (size_t)rgl * 256 + cbs);
        }
    };
    auto loadB = [&](int k, bf16x8 (&B)[16]) {
        const u16* wk = wt + k * 16384;
        LOADB(B[0], b0a, 0);
        LOADB(B[1], b0a, 1024);
        LOADB(B[2], b1a, 0);
        LOADB(B[3], b1a, 1024);
        LOADB(B[4], b0a, 2048);
        LOADB(B[5], b0a, 3072);
        LOADB(B[6], b1a, 2048);
        LOADB(B[7], b1a, 3072);
        LOADB(B[8], b0b, 0);
        LOADB(B[9], b0b, 1024);
        LOADB(B[10], b1b, 0);
        LOADB(B[11], b1b, 1024);
        LOADB(B[12], b0b, 2048);
        LOADB(B[13], b0b, 3072);
        LOADB(B[14], b1b, 2048);
        LOADB(B[15], b1b, 3072);
    };

    bf16x8 Ba[16], Bb[16];
    stageA(k0, 0);
    loadB(k0, Ba);

    auto body = [&](bf16x8 (&Bc)[16], bf16x8 (&Bn)[16], int k) {
        const int ab = (k - k0) & 1;
        if (k + 1 < k1) {
            stageA(k + 1, ab ^ 1);
            loadB(k + 1, Bn);
            asm volatile("s_waitcnt vmcnt(24)" ::: "memory");
        } else {
            asm volatile("s_waitcnt vmcnt(0)" ::: "memory");
        }
        __builtin_amdgcn_sched_barrier(0);
        const char* AsW = (const char*)&Asb[ab][wid][0];
        __builtin_amdgcn_s_setprio(1);
#pragma unroll
        for (int kk = 0; kk < 4; ++kk) {
            bf16x8 av[2];
#pragma unroll
            for (int m = 0; m < 2; ++m) {
                int row = m * 16 + lrow;
                int cb = (kk * 64 + lkb) ^ ((row & 7) << 4);
                av[m] = *(const bf16x8*)(AsW + row * 256 + cb);
            }
#pragma unroll
            for (int m = 0; m < 2; ++m)
#pragma unroll
                for (int n = 0; n < 4; ++n)
                    acc[m][n] = __builtin_amdgcn_mfma_f32_16x16x32_bf16(
                        av[m], Bc[n * 4 + kk], acc[m][n], 0, 0, 0);
        }
        __builtin_amdgcn_s_setprio(0);
    };

    int k = k0;
    while (true) {
        body(Ba, Bb, k);
        if (++k >= k1) break;
        body(Bb, Ba, k);
        if (++k >= k1) break;
    }

    if constexpr (PARTIAL) {
        float* pg = pout + (size_t)g * npts * 128;
#pragma unroll
        for (int m = 0; m < 2; ++m) {
            int prow = p0 + rg0 + m * 16 + (lane >> 4) * 4;
#pragma unroll
            for (int n = 0; n < 4; ++n) {
                int dcol = cg * 64 + n * 16 + lrow;
#pragma unroll
                for (int q = 0; q < 4; ++q)
                    pg[(prow + q) * 128 + dcol] = acc[m][n][q];
            }
        }
    } else {
#pragma unroll
        for (int m = 0; m < 2; ++m) {
            int prow = p0 + rg0 + m * 16 + (lane >> 4) * 4;
#pragma unroll
            for (int n = 0; n < 4; ++n) {
                int dcol = cg * 64 + n * 16 + lrow;
#pragma unroll
                for (int q = 0; q < 4; ++q) {
                    float v = acc[m][n][q];
                    int p = prow + q;
                    if (res) v += bf2f(res[p * 128 + dcol]);
                    v = v > 0.f ? v : 0.f;
                    fout[p * 128 + dcol] = f2bf(v);
                }
            }
        }
    }
}

// ---------------------------------------------------------------------------
// conv9 (fp8 children): BM=32, 4 waves, 4 blocks/CU, wave-K-split (conv6's
// proven sync skeleton).  Wave (kslc=wid>>1, cg=wid&1): rows 0..31 x cols
// cg*64..+64 over channels kslc*64..+64 via mfma_f32_16x16x32_fp8_fp8.
// A: LDS dbuf 2x4KB (1 async16/stage, swizzled source byte^=(row&7)<<4).
// B: 4 dwordx4 coalesced loads/offset from W3 (single-buffered regs).
// Per-iter VMEM: loadB 4 + stageA(k+1) 1 -> vmcnt(1) = A(k)+B(k) landed.
// Cross-wave K-reduce via red[4096].  LASTBF16: write u16 for the heads.
// ---------------------------------------------------------------------------
template <bool LASTBF16>
__global__ __launch_bounds__(256, 4) void conv9(
    const u8* __restrict__ fin, const int* __restrict__ nbr,
    const u8* __restrict__ wt, const u8* __restrict__ res,
    void* __restrict__ fout_) {
    constexpr int BM = 32;
    __shared__ __align__(16) u8 Asb[2][BM * 128];  // 2 x 4KB
    __shared__ float red[4096];                    // 16KB
    __shared__ int nbrS[BM * KOFF];                // 3456B
    const int tid = threadIdx.x;
    const int wid = tid >> 6;
    const int lane = tid & 63;
    const int p0 = blockIdx.x * BM;

    for (int i = tid; i < BM * KOFF; i += 256)
        nbrS[i] = nbr[(p0 + i / KOFF) * KOFF + (i % KOFF)];
    __syncthreads();  // vmcnt==0 past this point

    f32x4 acc[2][4];
#pragma unroll
    for (int m = 0; m < 2; ++m)
#pragma unroll
        for (int n = 0; n < 4; ++n) acc[m][n] = f32x4{0.f, 0.f, 0.f, 0.f};

    const int kslc = wid >> 1;      // channel half
    const int CB = (wid & 1) * 64;  // col half
    const int lrow = lane & 15;
    const int vb = (kslc * 2 + (wid & 1)) * 4096 + lane * 16;

    auto stageA = [&](int k, int buf) {
        int rl = wid * 8 + (lane >> 3);  // local row staged by this lane
        int boff = (lane & 7) * 16;
        int rg = nbrS[rl * KOFF + k];
        async16((char*)&Asb[buf][0] + wid * 1024,
                (const char*)fin + (size_t)rg * 128 + (boff ^ ((rl & 7) << 4)));
    };

    lx2 B4[4];
    stageA(0, 0);

#pragma unroll 1
    for (int k = 0; k < KOFF; ++k) {
        const int ab = k & 1;
        __builtin_amdgcn_s_barrier();  // all waves done reading Asb[ab^1]
        {
            const u8* wk = wt + k * 16384;
            LOADB(B4[0], vb, 0);
            LOADB(B4[1], vb, 1024);
            LOADB(B4[2], vb, 2048);
            LOADB(B4[3], vb, 3072);
        }
        if (k + 1 < KOFF) {
            stageA(k + 1, ab ^ 1);
            asm volatile("s_waitcnt vmcnt(1)" ::: "memory");  // A(k),B(k) done
        } else {
            asm volatile("s_waitcnt vmcnt(0)" ::: "memory");
        }
        __builtin_amdgcn_s_barrier();       // all waves' A rows visible
        __builtin_amdgcn_sched_barrier(0);  // no ds_read hoisting above
        __builtin_amdgcn_s_setprio(1);
#pragma unroll
        for (int kk2 = 0; kk2 < 2; ++kk2) {
            long av[2];
#pragma unroll
            for (int m = 0; m < 2; ++m) {
                int row = m * 16 + lrow;
                int off = (kslc * 64 + kk2 * 32 + (lane >> 4) * 8) ^
                          ((row & 7) << 4);
                av[m] = *(const long*)((const char*)&Asb[ab][0] + row * 128 + off);
            }
#pragma unroll
            for (int m = 0; m < 2; ++m)
#pragma unroll
                for (int n = 0; n < 4; ++n)
                    acc[m][n] = __builtin_amdgcn_mfma_f32_16x16x32_fp8_fp8(
                        av[m], B4[n][kk2], acc[m][n], 0, 0, 0);
        }
        __builtin_amdgcn_s_setprio(0);
    }

    // cross-wave reduce: kslc=1 waves dump, kslc=0 waves add + write.
    __syncthreads();
    if (kslc == 1) {
        const int base = (wid - 2) * 2048;
#pragma unroll
        for (int m = 0; m < 2; ++m)
#pragma unroll
            for (int n = 0; n < 4; ++n)
#pragma unroll
                for (int q = 0; q < 4; ++q)
                    red[base + (((m * 4 + n) * 4 + q) * 64) + lane] =
                        acc[m][n][q];
    }
    __syncthreads();
    if (kslc == 0) {
        const int base = wid * 2048;
#pragma unroll
        for (int m = 0; m < 2; ++m)
#pragma unroll
            for (int n = 0; n < 4; ++n)
#pragma unroll
                for (int q = 0; q < 4; ++q)
                    acc[m][n][q] +=
                        red[base + (((m * 4 + n) * 4 + q) * 64) + lane];
#pragma unroll
        for (int m = 0; m < 2; ++m) {
            int prow = p0 + m * 16 + (lane >> 4) * 4;
#pragma unroll
            for (int n = 0; n < 4; ++n) {
                int dcol = CB + n * 16 + lrow;
#pragma unroll
                for (int q = 0; q < 4; ++q) {
                    float v = acc[m][n][q];
                    int p = prow + q;
                    if (res) v += fp82f(res[p * 128 + dcol]);
                    v = v > 0.f ? v : 0.f;
                    if constexpr (LASTBF16)
                        ((u16*)fout_)[p * 128 + dcol] = f2bf(v);
                    else
                        ((u8*)fout_)[p * 128 + dcol] = f2fp8(v);
                }
            }
        }
    }
}

// combine split-K partials: out = relu(sum_g P[g] (+ res)) -> bf16
__global__ __launch_bounds__(256) void combine_k(const float* __restrict__ P,
                                                 const u16* __restrict__ res,
                                                 u16* __restrict__ fout,
                                                 int nelem) {
    int base = (blockIdx.x * 256 + threadIdx.x) * 4;
    f32x4 s = *(const f32x4*)(P + base);
#pragma unroll
    for (int gg = 1; gg < 8; ++gg)
        s += *(const f32x4*)(P + (size_t)gg * nelem + base);
    u16x4 o;
    if (res) {
        u16x4 rv = *(const u16x4*)(res + base);
#pragma unroll
        for (int j = 0; j < 4; ++j) s[j] += bf2f(rv[j]);
    }
#pragma unroll
    for (int j = 0; j < 4; ++j) {
        float v = s[j] > 0.f ? s[j] : 0.f;
        o[j] = f2bf(v);
    }
    *(u16x4*)(fout + base) = o;
}

// ---------------------------------------------------------------------------
// Fused heads: one block = 128 points (unchanged, proven).
// ---------------------------------------------------------------------------
__global__ __launch_bounds__(512, 1) void fused_heads(
    const u16* __restrict__ G, const int* __restrict__ gtO,
    const u16* __restrict__ wt2, const u16* __restrict__ wt2h,
    const float* __restrict__ b1a, const float* __restrict__ b1b,
    const float* __restrict__ E1, const float* __restrict__ b2a,
    const float* __restrict__ b2b, float* __restrict__ partial) {
    __shared__ __align__(16) u16 AB[49152];   // 96KB: A 32K | B 64K
    __shared__ __align__(16) u16 W2ts[4096];  // 8KB
    __shared__ float E1s[2048];
    __shared__ float b2s[32];
    __shared__ int gts[256];
    __shared__ float bitsS[256];
    u16* Asb = AB;
    u16* Bsb = AB + 16384;
    char* Hb = (char*)AB;
    const int tid = threadIdx.x, wid = tid >> 6, lane = tid & 63;
    const int lrow = lane & 15, lkb = (lane >> 4) * 16;
    const int p0 = blockIdx.x * 128;

#pragma unroll
    for (int i = 0; i < 4; ++i) {
        int o = i * 8192 + tid * 16;
        int r = o >> 8;
        int cbs = (o & 255) ^ ((r & 7) << 4);
        async16((char*)Asb + i * 8192 + wid * 1024,
                (const char*)G + (size_t)(p0 + r) * 256 + cbs);
    }
#pragma unroll
    for (int i = 0; i < 8; ++i)
        async16((char*)Bsb + i * 8192 + wid * 1024,
                (const char*)wt2 + i * 8192 + tid * 16);
    async16((char*)W2ts + wid * 1024, (const char*)wt2h + tid * 16);
    for (int i = tid; i < 2048; i += 512) E1s[i] = E1[i];
    if (tid < 16) b2s[tid] = b2a[tid];
    else if (tid < 32) b2s[tid] = b2b[tid - 16];
    if (tid < 128) {
        int g = gtO[p0 + tid];
        gts[tid] = g & 15;
        gts[128 + tid] = g >> 4;
    }
    __syncthreads();

    const int RB = (wid >> 1) * 32, CB = (wid & 1) * 128;
    f32x4 acc[2][8];
#pragma unroll
    for (int m = 0; m < 2; ++m)
#pragma unroll
        for (int n = 0; n < 8; ++n) acc[m][n] = f32x4{0.f, 0.f, 0.f, 0.f};
    __builtin_amdgcn_s_setprio(1);
#pragma unroll
    for (int kk = 0; kk < 4; ++kk) {
        bf16x8 av[2], bv[8];
#pragma unroll
        for (int m = 0; m < 2; ++m) {
            int row = RB + m * 16 + lrow;
            int cb = (kk * 64 + lkb) ^ ((row & 7) << 4);
            av[m] = *(const bf16x8*)((const char*)Asb + row * 256 + cb);
        }
#pragma unroll
        for (int n = 0; n < 8; ++n) {
            int drow = CB + n * 16 + lrow;
            int cb = (kk * 64 + lkb) ^ ((drow & 7) << 4);
            bv[n] = *(const bf16x8*)((const char*)Bsb + drow * 256 + cb);
        }
#pragma unroll
        for (int m = 0; m < 2; ++m)
#pragma unroll
            for (int n = 0; n < 8; ++n)
                acc[m][n] = __builtin_amdgcn_mfma_f32_16x16x32_bf16(
                    av[m], bv[n], acc[m][n], 0, 0, 0);
    }
    __builtin_amdgcn_s_setprio(0);
    __syncthreads();

    const float* b1p = CB ? b1b : b1a;
    float b1v[8];
#pragma unroll
    for (int n = 0; n < 8; ++n) b1v[n] = b1p[n * 16 + lrow];
#pragma unroll
    for (int m = 0; m < 2; ++m) {
#pragma unroll
        for (int q = 0; q < 4; ++q) {
            int p = RB + m * 16 + (lane >> 4) * 4 + q;
#pragma unroll
            for (int n = 0; n < 8; ++n) {
                float v = acc[m][n][q] + b1v[n];
                if (CB) v += E1s[gts[p] * 128 + n * 16 + lrow];
                v = v > 0.f ? v : 0.f;
                int colb = (CB + n * 16 + lrow) * 2;
                *(u16*)(Hb + p * 512 + (colb ^ ((p & 7) << 4))) = f2bf(v);
            }
        }
    }
    __syncthreads();

    const int RB2 = wid * 16;
    f32x4 acc2[2];
    acc2[0] = f32x4{0.f, 0.f, 0.f, 0.f};
    acc2[1] = f32x4{0.f, 0.f, 0.f, 0.f};
#pragma unroll
    for (int kk = 0; kk < 4; ++kk) {
        int row = RB2 + lrow;
        int cb = (kk * 64 + lkb) ^ ((row & 7) << 4);
        int cbw = (kk * 64 + lkb) ^ ((lrow & 7) << 4);
#pragma unroll
        for (int h = 0; h < 2; ++h) {
            bf16x8 a2 = *(const bf16x8*)(Hb + row * 512 + h * 256 + cb);
            bf16x8 b2v = *(const bf16x8*)((const char*)W2ts + h * 4096 +
                                          lrow * 256 + cbw);
            acc2[h] = __builtin_amdgcn_mfma_f32_16x16x32_bf16(a2, b2v, acc2[h],
                                                              0, 0, 0);
        }
    }
    const int jj = lrow;
#pragma unroll
    for (int h = 0; h < 2; ++h) {
#pragma unroll
        for (int q = 0; q < 4; ++q) {
            int pt = RB2 + (lane >> 4) * 4 + q;
            float v = acc2[h][q] + b2s[h * 16 + jj];
            float mx = v;
#pragma unroll
            for (int o = 1; o < 16; o <<= 1) mx = fmaxf(mx, __shfl_xor(mx, o, 16));
            float e = expf(v - mx);
            float s = e;
#pragma unroll
            for (int o = 1; o < 16; o <<= 1) s += __shfl_xor(s, o, 16);
            float bits = -log2f(e / s + 1e-10f);
            bits = fminf(fmaxf(bits, 0.f), 50.f);
            if (jj == gts[h * 128 + pt]) bitsS[h * 128 + pt] = bits;
        }
    }
    __syncthreads();
    if (tid < 64) {
        float s = bitsS[tid] + bitsS[tid + 64] + bitsS[tid + 128] + bitsS[tid + 192];
#pragma unroll
        for (int o = 32; o > 0; o >>= 1) s += __shfl_down(s, o, 64);
        if (tid == 0) partial[blockIdx.x] = s;
    }
}

__global__ __launch_bounds__(256) void finalize_k(const float* __restrict__ partial,
                                                  float* __restrict__ out, int n) {
    float s = 0.f;
    for (int i = threadIdx.x; i < n; i += 256) s += partial[i];
#pragma unroll
    for (int o = 32; o > 0; o >>= 1) s += __shfl_down(s, o, 64);
    __shared__ float wsum[4];
    if ((threadIdx.x & 63) == 0) wsum[threadIdx.x >> 6] = s;
    __syncthreads();
    if (threadIdx.x == 0)
        out[0] = (wsum[0] + wsum[1] + wsum[2] + wsum[3]) * (1.0f / 4096.0f);
}

// ---------------------------------------------------------------------------
extern "C" void kernel_launch(void* const* d_in, const int* in_sizes, int n_in,
                              void* d_out, int out_size, void* d_ws,
                              size_t ws_size, hipStream_t stream) {
    const int N = 4096, M = 32768;
    const int* x_O = (const int*)d_in[0];
    const int* gt_O = (const int*)d_in[1];
    const int* nbr_par = (const int*)d_in[2];
    const int* nbr_ch = (const int*)d_in[3];
    const int* child_oct = (const int*)d_in[4];
    const float* prior_emb = (const float*)d_in[5];
    const float* convW[10] = {
        (const float*)d_in[6],  (const float*)d_in[7],  (const float*)d_in[8],
        (const float*)d_in[9],  (const float*)d_in[10], (const float*)d_in[12],
        (const float*)d_in[13], (const float*)d_in[14], (const float*)d_in[15],
        (const float*)d_in[16]};
    const float* oct_emb = (const float*)d_in[11];
    const float* s1_emb = (const float*)d_in[17];
    const float* h0W1 = (const float*)d_in[18];
    const float* h0b1 = (const float*)d_in[19];
    const float* h0W2 = (const float*)d_in[20];
    const float* h0b2 = (const float*)d_in[21];
    const float* h1W1 = (const float*)d_in[22];
    const float* h1b1 = (const float*)d_in[23];
    const float* h1W2 = (const float*)d_in[24];
    const float* h1b2 = (const float*)d_in[25];

    char* ws = (char*)d_ws;
    size_t off = 0;
    auto alloc = [&](size_t b) {
        void* p = ws + off;
        off += (b + 255) & ~(size_t)255;
        return p;
    };
    PrepArgs pa;
    for (int i = 0; i < 10; ++i) pa.ws[i] = convW[i];
    for (int i = 0; i < 5; ++i) pa.wd[i] = (u16*)alloc(27 * 128 * 128 * 2);
    for (int i = 5; i < 10; ++i) pa.wd[i] = nullptr;
    for (int i = 0; i < 5; ++i) pa.wd3[i] = (u8*)alloc(27 * 128 * 128);
    u16* Wt2 = (u16*)alloc(256 * 128 * 2);
    pa.ws[10] = h0W1;
    pa.ws[11] = h1W1;
    pa.wd[10] = Wt2;
    pa.wd[11] = Wt2 + 128 * 128;
    u16* wt2h = (u16*)alloc(2 * 16 * 128 * 2);
    float* E1 = (float*)alloc(16 * 128 * 4);
    pa.h0W2 = h0W2;
    pa.h1W2 = h1W2;
    pa.wt2h = wt2h;
    pa.s1emb = s1_emb;
    pa.h1W1f = h1W1;
    pa.E1 = E1;

    u16* fA = (u16*)alloc((size_t)N * 256);
    u16* fB = (u16*)alloc((size_t)N * 256);
    u16* fC = (u16*)alloc((size_t)N * 256);
    // fp8 child features (4MB each) + bf16 head input (8MB), contiguous so
    // the 16MB parent split-K partial buffer can alias them (dead until
    // expand8 runs after the parent stack completes).
    u8* g8A = (u8*)alloc((size_t)M * 128);
    u8* g8B = (u8*)alloc((size_t)M * 128);
    u8* g8C = (u8*)alloc((size_t)M * 128);
    u16* gBF = (u16*)alloc((size_t)M * 256);
    float* partial = (float*)alloc(256 * 4);
    float* pconv = (float*)g8A;

    prep_mega<<<554, 256, 0, stream>>>(pa);
    embed_k<<<N * 128 / 256, 256, 0, stream>>>(x_O, prior_emb, fA);

    const int PE = N * 128;
    // parent stack: conv7 split-K over 8 offset groups (PROVEN R10)
    conv7<true><<<dim3(64, 8), 256, 0, stream>>>(fA, nbr_par, pa.wd[0], nullptr, nullptr, pconv, N);
    combine_k<<<PE / 1024, 256, 0, stream>>>(pconv, nullptr, fB, PE);
    conv7<true><<<dim3(64, 8), 256, 0, stream>>>(fB, nbr_par, pa.wd[1], nullptr, nullptr, pconv, N);
    combine_k<<<PE / 1024, 256, 0, stream>>>(pconv, nullptr, fC, PE);
    conv7<true><<<dim3(64, 8), 256, 0, stream>>>(fC, nbr_par, pa.wd[2], nullptr, nullptr, pconv, N);
    combine_k<<<PE / 1024, 256, 0, stream>>>(pconv, fB, fA, PE);
    conv7<true><<<dim3(64, 8), 256, 0, stream>>>(fA, nbr_par, pa.wd[3], nullptr, nullptr, pconv, N);
    combine_k<<<PE / 1024, 256, 0, stream>>>(pconv, nullptr, fC, PE);
    conv7<true><<<dim3(64, 8), 256, 0, stream>>>(fC, nbr_par, pa.wd[4], nullptr, nullptr, pconv, N);
    combine_k<<<PE / 1024, 256, 0, stream>>>(pconv, fA, fB, PE);

    // expand to children (fp8)
    expand8<<<M * 128 / 256, 256, 0, stream>>>(fB, child_oct, oct_emb, g8A);

    // child stack: fp8, 1024 blocks (4 per CU); last layer emits bf16
    conv9<false><<<1024, 256, 0, stream>>>(g8A, nbr_ch, pa.wd3[0], nullptr, g8B);
    conv9<false><<<1024, 256, 0, stream>>>(g8B, nbr_ch, pa.wd3[1], nullptr, g8C);
    conv9<false><<<1024, 256, 0, stream>>>(g8C, nbr_ch, pa.wd3[2], g8B, g8A);
    conv9<false><<<1024, 256, 0, stream>>>(g8A, nbr_ch, pa.wd3[3], nullptr, g8C);
    conv9<true><<<1024, 256, 0, stream>>>(g8C, nbr_ch, pa.wd3[4], g8A, gBF);

    fused_heads<<<M / 128, 512, 0, stream>>>(gBF, gt_O, Wt2, wt2h, h0b1, h1b1,
                                             E1, h0b2, h1b2, partial);
    finalize_k<<<1, 256, 0, stream>>>(partial, (float*)d_out, 256);

    (void)in_sizes; (void)n_in; (void)out_size; (void)ws_size;
}